// Round 1
// baseline (771.921 us; speedup 1.0000x reference)
//
#include <hip/hip_runtime.h>
#include <math.h>

#define B_ 8
#define S_ 1024
#define D_ 1024
#define H_ 8
#define DH_ 128

typedef __bf16 bf16;
typedef __attribute__((ext_vector_type(8))) __bf16 bf16x8;
typedef __attribute__((ext_vector_type(4))) float f32x4;

#define MFMA16(a, b, c) __builtin_amdgcn_mfma_f32_16x16x32_bf16((a), (b), (c), 0, 0, 0)

// ---------------------------------------------------------------------------
// Projection GEMM: out[m,n] = sum_k X[m,k] * W[n,k] + bias[n], bf16 output.
// M=8192, N=1024, K=1024. Tile 128x128, BK=64, 4 waves (2x2), each 64x64.
// LDS XOR-swizzle: 16B-chunk ^= (row&7)  -> conflict-free ds_read_b128.
// ---------------------------------------------------------------------------
__global__ __launch_bounds__(256) void proj_kernel(
    const float* __restrict__ X, const float* __restrict__ W,
    const float* __restrict__ bias, bf16* __restrict__ out)
{
    __shared__ __align__(16) bf16 ldsA[128 * 64];
    __shared__ __align__(16) bf16 ldsB[128 * 64];
    const int tid  = threadIdx.x;
    const int lane = tid & 63;
    const int l15  = lane & 15, l4 = lane >> 4;
    const int wave = tid >> 6;
    const int wr   = wave >> 1, wc = wave & 1;
    const int n0   = blockIdx.x * 128;   // N fastest -> consecutive blocks share X panel (L2)
    const int m0   = blockIdx.y * 128;

    f32x4 acc[4][4];
#pragma unroll
    for (int i = 0; i < 4; ++i)
#pragma unroll
        for (int j = 0; j < 4; ++j) acc[i][j] = (f32x4){0.f, 0.f, 0.f, 0.f};

    for (int k0 = 0; k0 < 1024; k0 += 64) {
        // stage A (X rows) and B (W rows): 128x64 each, fp32 -> bf16
#pragma unroll
        for (int rep = 0; rep < 4; ++rep) {
            int idx = rep * 256 + tid;          // 0..1023 chunk id
            int row = idx >> 3;                 // 0..127
            int ch  = idx & 7;                  // 8 chunks of 8 elems per row
            const float* sa = X + (size_t)(m0 + row) * 1024 + k0 + ch * 8;
            const float* sb = W + (size_t)(n0 + row) * 1024 + k0 + ch * 8;
            f32x4 a0 = *(const f32x4*)sa;
            f32x4 a1 = *(const f32x4*)(sa + 4);
            f32x4 b0 = *(const f32x4*)sb;
            f32x4 b1 = *(const f32x4*)(sb + 4);
            bf16x8 av, bv;
#pragma unroll
            for (int j = 0; j < 4; ++j) {
                av[j] = (bf16)a0[j]; av[4 + j] = (bf16)a1[j];
                bv[j] = (bf16)b0[j]; bv[4 + j] = (bf16)b1[j];
            }
            int sch = ch ^ (row & 7);
            *(bf16x8*)&ldsA[row * 64 + sch * 8] = av;
            *(bf16x8*)&ldsB[row * 64 + sch * 8] = bv;
        }
        __syncthreads();
#pragma unroll
        for (int ks = 0; ks < 2; ++ks) {
            bf16x8 af[4], bfr[4];
            int ch = ks * 4 + l4;
#pragma unroll
            for (int mi = 0; mi < 4; ++mi) {
                int row = wr * 64 + mi * 16 + l15;
                af[mi] = *(const bf16x8*)&ldsA[row * 64 + ((ch ^ (row & 7)) << 3)];
            }
#pragma unroll
            for (int ni = 0; ni < 4; ++ni) {
                int row = wc * 64 + ni * 16 + l15;
                bfr[ni] = *(const bf16x8*)&ldsB[row * 64 + ((ch ^ (row & 7)) << 3)];
            }
#pragma unroll
            for (int mi = 0; mi < 4; ++mi)
#pragma unroll
                for (int ni = 0; ni < 4; ++ni)
                    acc[mi][ni] = MFMA16(af[mi], bfr[ni], acc[mi][ni]);
        }
        __syncthreads();
    }
    // epilogue: bias + bf16 store. C layout: col = l15, row = l4*4 + reg.
#pragma unroll
    for (int ni = 0; ni < 4; ++ni) {
        float bval = bias[n0 + wc * 64 + ni * 16 + l15];
        int n = n0 + wc * 64 + ni * 16 + l15;
#pragma unroll
        for (int mi = 0; mi < 4; ++mi) {
#pragma unroll
            for (int r = 0; r < 4; ++r) {
                int m = m0 + wr * 64 + mi * 16 + l4 * 4 + r;
                out[(size_t)m * 1024 + n] = (bf16)(acc[mi][ni][r] + bval);
            }
        }
    }
}

// ---------------------------------------------------------------------------
// vp [B,S,H*128] (bf16) -> vpT [B,H,128,S] (bf16) so PV B-frags are 16B loads
// ---------------------------------------------------------------------------
__global__ __launch_bounds__(256) void transpose_v(
    const bf16* __restrict__ vp, bf16* __restrict__ vpT)
{
    __shared__ __align__(16) bf16 t[64][80];   // pad to 160B rows (16B-aligned)
    const int tid = threadIdx.x;
    const int s0 = blockIdx.x * 64;
    const int db = blockIdx.y * 64;
    const int bh = blockIdx.z;
    const int b = bh >> 3, h = bh & 7;
#pragma unroll
    for (int rep = 0; rep < 2; ++rep) {
        int r = rep * 32 + (tid >> 3);
        int c = (tid & 7) * 8;
        bf16x8 val = *(const bf16x8*)(vp + (size_t)(b * 1024 + s0 + r) * 1024 + h * 128 + db + c);
        *(bf16x8*)&t[r][c] = val;
    }
    __syncthreads();
#pragma unroll
    for (int rep = 0; rep < 2; ++rep) {
        int dd = rep * 32 + (tid >> 3);
        int sc = (tid & 7) * 8;
        bf16x8 o;
#pragma unroll
        for (int j = 0; j < 8; ++j) o[j] = t[sc + j][dd];
        *(bf16x8*)(vpT + (size_t)((b * 8 + h) * 128 + db + dd) * 1024 + s0 + sc) = o;
    }
}

// ---------------------------------------------------------------------------
// Fused attention: per block = (b, h, 64 q-rows). 4 waves x 16 q-rows each.
// Flash loop over 64-key tiles: QK^T MFMA -> mask/scale -> raw-score write ->
// online softmax (16-lane shuffle reduce) -> P via LDS -> PV MFMA -> fused
// out-projection (ctx @ Wo^T + bo).
// ---------------------------------------------------------------------------
__global__ __launch_bounds__(256) void attn_kernel(
    const bf16* __restrict__ qp, const bf16* __restrict__ kp,
    const bf16* __restrict__ vpT, const int* __restrict__ mask,
    const float* __restrict__ Wo, const float* __restrict__ bo,
    float* __restrict__ out0, float* __restrict__ raw)
{
    __shared__ __align__(16) bf16 work[4][16 * 128];  // per-wave scratch (P tile / ctx tile)
    const int tid  = threadIdx.x;
    const int lane = tid & 63;
    const int l15  = lane & 15, l4 = lane >> 4;
    const int wave = tid >> 6;
    const int qt = blockIdx.x, h = blockIdx.y, b = blockIdx.z;
    const int q0 = qt * 64 + wave * 16;

    // Q fragments for this wave's 16 rows (row = l15, k = 32*ks + 8*l4 + j)
    bf16x8 qf[4];
    const bf16* qbase = qp + (size_t)(b * 1024 + q0 + l15) * 1024 + h * 128 + l4 * 8;
#pragma unroll
    for (int ks = 0; ks < 4; ++ks) qf[ks] = *(const bf16x8*)(qbase + ks * 32);

    f32x4 ctx[8];
#pragma unroll
    for (int i = 0; i < 8; ++i) ctx[i] = (f32x4){0.f, 0.f, 0.f, 0.f};
    float m_run[4] = {-INFINITY, -INFINITY, -INFINITY, -INFINITY};
    float l_run[4] = {0.f, 0.f, 0.f, 0.f};

    const float scale = 0.08838834764831845f;  // 1/sqrt(128)

    for (int kb = 0; kb < 1024; kb += 64) {
        // ---- QK^T: s[nf] covers keys kb + nf*16 + l15, rows q0 + l4*4 + r
        f32x4 s[4];
#pragma unroll
        for (int nf = 0; nf < 4; ++nf) {
            int key = kb + nf * 16 + l15;
            const bf16* kbase = kp + (size_t)(b * 1024 + key) * 1024 + h * 128 + l4 * 8;
            f32x4 a = (f32x4){0.f, 0.f, 0.f, 0.f};
#pragma unroll
            for (int ks = 0; ks < 4; ++ks)
                a = MFMA16(qf[ks], *(const bf16x8*)(kbase + ks * 32), a);
            int mv = mask[b * 1024 + key];
#pragma unroll
            for (int r = 0; r < 4; ++r) s[nf][r] = mv ? a[r] * scale : -1e9f;
        }
        // ---- raw (pre-softmax, masked) score output: raw[b, q, h*1024 + key]
#pragma unroll
        for (int nf = 0; nf < 4; ++nf) {
            int key = kb + nf * 16 + l15;
#pragma unroll
            for (int r = 0; r < 4; ++r) {
                int qrow = q0 + l4 * 4 + r;
                raw[(size_t)(b * 1024 + qrow) * 8192 + h * 1024 + key] = s[nf][r];
            }
        }
        // ---- online softmax update (per row r; 16-lane group shares a row set)
#pragma unroll
        for (int r = 0; r < 4; ++r) {
            float pm = fmaxf(fmaxf(s[0][r], s[1][r]), fmaxf(s[2][r], s[3][r]));
            pm = fmaxf(pm, __shfl_xor(pm, 1));
            pm = fmaxf(pm, __shfl_xor(pm, 2));
            pm = fmaxf(pm, __shfl_xor(pm, 4));
            pm = fmaxf(pm, __shfl_xor(pm, 8));
            float mn = fmaxf(m_run[r], pm);
            float alpha = __expf(m_run[r] - mn);
            m_run[r] = mn;
            float rs = 0.f;
#pragma unroll
            for (int nf = 0; nf < 4; ++nf) {
                float p = __expf(s[nf][r] - mn);
                s[nf][r] = p;
                rs += p;
            }
            rs += __shfl_xor(rs, 1);
            rs += __shfl_xor(rs, 2);
            rs += __shfl_xor(rs, 4);
            rs += __shfl_xor(rs, 8);
            l_run[r] = l_run[r] * alpha + rs;
#pragma unroll
            for (int df = 0; df < 8; ++df) ctx[df][r] *= alpha;
        }
        // ---- P -> LDS (bf16, [16 q][64 key], 16B-chunk ^= q&7)
#pragma unroll
        for (int nf = 0; nf < 4; ++nf) {
#pragma unroll
            for (int r = 0; r < 4; ++r) {
                int qw = l4 * 4 + r;
                int keyl = nf * 16 + l15;
                int chw = keyl >> 3;
                work[wave][qw * 64 + ((chw ^ (qw & 7)) << 3) + (keyl & 7)] = (bf16)s[nf][r];
            }
        }
        // ---- PV: ctx[df] += P @ V  (A from LDS, B from vpT contiguous)
#pragma unroll
        for (int kstep = 0; kstep < 2; ++kstep) {
            int ch = kstep * 4 + l4;
            bf16x8 pf = *(const bf16x8*)&work[wave][l15 * 64 + ((ch ^ (l15 & 7)) << 3)];
#pragma unroll
            for (int df = 0; df < 8; ++df) {
                const bf16* vb = vpT + (size_t)((b * 8 + h) * 128 + df * 16 + l15) * 1024
                                 + kb + kstep * 32 + l4 * 8;
                ctx[df] = MFMA16(pf, *(const bf16x8*)vb, ctx[df]);
            }
        }
    }

    // ---- normalize, park ctx in LDS ([16 q][128 d], chunk ^= q&7 on low 3 bits)
    float invl[4];
#pragma unroll
    for (int r = 0; r < 4; ++r) invl[r] = 1.0f / l_run[r];
#pragma unroll
    for (int df = 0; df < 8; ++df) {
#pragma unroll
        for (int r = 0; r < 4; ++r) {
            int qw = l4 * 4 + r;
            int dcol = df * 16 + l15;
            int chw = dcol >> 3;
            work[wave][qw * 128 + ((chw ^ (qw & 7)) << 3) + (dcol & 7)] =
                (bf16)(ctx[df][r] * invl[r]);
        }
    }
    // ---- out-proj: out[q,e] = sum_d ctxn[q,d] * Wo[e,d] + bo[e]
    f32x4 oacc[8];
#pragma unroll
    for (int i = 0; i < 8; ++i) oacc[i] = (f32x4){0.f, 0.f, 0.f, 0.f};
#pragma unroll
    for (int ks = 0; ks < 4; ++ks) {
        int ch = ks * 4 + l4;
        bf16x8 cf = *(const bf16x8*)&work[wave][l15 * 128 + ((ch ^ (l15 & 7)) << 3)];
#pragma unroll
        for (int ef = 0; ef < 8; ++ef) {
            const float* wsrc = Wo + (ef * 16 + l15) * 128 + ks * 32 + l4 * 8;
            bf16x8 wf;
#pragma unroll
            for (int j = 0; j < 8; ++j) wf[j] = (bf16)wsrc[j];
            oacc[ef] = MFMA16(cf, wf, oacc[ef]);
        }
    }
#pragma unroll
    for (int ef = 0; ef < 8; ++ef) {
        float bias = bo[ef * 16 + l15];
#pragma unroll
        for (int r = 0; r < 4; ++r) {
            int qrow = q0 + l4 * 4 + r;
            out0[(size_t)(b * 1024 + qrow) * 1024 + h * 128 + ef * 16 + l15] =
                oacc[ef][r] + bias;
        }
    }
}

extern "C" void kernel_launch(void* const* d_in, const int* in_sizes, int n_in,
                              void* d_out, int out_size, void* d_ws, size_t ws_size,
                              hipStream_t stream) {
    const float* q    = (const float*)d_in[0];
    const float* k    = (const float*)d_in[1];
    const float* v    = (const float*)d_in[2];
    const int*   mask = (const int*)d_in[3];
    const float* Wq   = (const float*)d_in[4];
    const float* bq   = (const float*)d_in[5];
    const float* Wk   = (const float*)d_in[6];
    const float* bk   = (const float*)d_in[7];
    const float* Wv   = (const float*)d_in[8];
    const float* bv   = (const float*)d_in[9];
    const float* Wo   = (const float*)d_in[10];
    const float* bo   = (const float*)d_in[11];

    float* out0 = (float*)d_out;                       // [B,S,D] = 8,388,608 floats
    float* raw  = out0 + (size_t)B_ * S_ * D_;         // [B,S,H*S] = 67,108,864 floats

    const size_t NE = (size_t)B_ * S_ * D_;            // 8,388,608 elements per projection
    bf16* qp  = (bf16*)d_ws;
    bf16* kp  = qp + NE;
    bf16* vpT = kp + NE;
    // Park natural-layout vp in the TAIL of d_out's raw region (bf16 = 16 MiB).
    // It is consumed by transpose_v before attn_kernel overwrites raw.
    bf16* vp = (bf16*)((char*)d_out + (size_t)75497472 * 4 - NE * 2);

    dim3 pg(8, 64);  // x = n-block (fast -> shared X panel in L2), y = m-block
    proj_kernel<<<pg, 256, 0, stream>>>(q, Wq, bq, qp);
    proj_kernel<<<pg, 256, 0, stream>>>(k, Wk, bk, kp);
    proj_kernel<<<pg, 256, 0, stream>>>(v, Wv, bv, vp);
    transpose_v<<<dim3(16, 2, 64), 256, 0, stream>>>(vp, vpT);
    attn_kernel<<<dim3(16, 8, 8), 256, 0, stream>>>(qp, kp, vpT, mask, Wo, bo, out0, raw);
}

// Round 3
// 638.376 us; speedup vs baseline: 1.2092x; 1.2092x over previous
//
#include <hip/hip_runtime.h>
#include <math.h>

#define B_ 8
#define S_ 1024
#define D_ 1024
#define H_ 8

typedef __bf16 bf16;
typedef __attribute__((ext_vector_type(8))) __bf16 bf16x8;
typedef __attribute__((ext_vector_type(4))) float f32x4;

#define MFMA16(a, b, c) __builtin_amdgcn_mfma_f32_16x16x32_bf16((a), (b), (c), 0, 0, 0)
#define GLOAD_LDS16(src, dst)                                                            \
    __builtin_amdgcn_global_load_lds((const __attribute__((address_space(1))) void*)(src), \
                                     (__attribute__((address_space(3))) void*)(dst), 16, 0, 0)

// ---------------------------------------------------------------------------
// cast fp32 -> bf16 for q,k,v (8.4M each) and Wq,Wk,Wv (1M each)
// ---------------------------------------------------------------------------
__global__ __launch_bounds__(256) void cast6(
    const float* __restrict__ q, const float* __restrict__ k, const float* __restrict__ v,
    const float* __restrict__ Wq, const float* __restrict__ Wk, const float* __restrict__ Wv,
    bf16* __restrict__ xq, bf16* __restrict__ xk, bf16* __restrict__ xv,
    bf16* __restrict__ wq, bf16* __restrict__ wk, bf16* __restrict__ wv)
{
    int t = blockIdx.y;
    const float* src;
    bf16* dst;
    size_t n;
    switch (t) {
        case 0: src = q;  dst = xq; n = 8388608; break;
        case 1: src = k;  dst = xk; n = 8388608; break;
        case 2: src = v;  dst = xv; n = 8388608; break;
        case 3: src = Wq; dst = wq; n = 1048576; break;
        case 4: src = Wk; dst = wk; n = 1048576; break;
        default: src = Wv; dst = wv; n = 1048576; break;
    }
    size_t i0 = ((size_t)blockIdx.x * 256 + threadIdx.x) * 8;
    if (i0 >= n) return;
    f32x4 a = *(const f32x4*)(src + i0);
    f32x4 b = *(const f32x4*)(src + i0 + 4);
    bf16x8 o;
#pragma unroll
    for (int j = 0; j < 4; ++j) { o[j] = (bf16)a[j]; o[4 + j] = (bf16)b[j]; }
    *(bf16x8*)(dst + i0) = o;
}

// ---------------------------------------------------------------------------
// bf16 GEMM: out[m,n] = X[m,:].W[n,:] + bias[n].  M=8192,N=1024,K=1024.
// m97 structure: 128x128 tile, BK=64, global_load_lds width16, linear LDS,
// 4 waves 2x2 (64x64 each). XCD-chunked block remap (8 m-panels x 8 n per XCD).
// ---------------------------------------------------------------------------
__global__ __launch_bounds__(256) void proj_bf16(
    const bf16* __restrict__ X, const bf16* __restrict__ W,
    const float* __restrict__ bias, bf16* __restrict__ out)
{
    __shared__ __align__(16) bf16 ldsA[128 * 64];
    __shared__ __align__(16) bf16 ldsB[128 * 64];
    const int tid  = threadIdx.x;
    const int lane = tid & 63;
    const int l15  = lane & 15, l4 = lane >> 4;
    const int wave = tid >> 6;
    const int wr   = wave >> 1, wc = wave & 1;

    int f   = blockIdx.x;            // 512 blocks
    int xcd = f & 7, idx = f >> 3;   // idx 0..63
    const int m0 = (xcd * 8 + (idx >> 3)) * 128;
    const int n0 = (idx & 7) * 128;

    f32x4 acc[4][4];
#pragma unroll
    for (int i = 0; i < 4; ++i)
#pragma unroll
        for (int j = 0; j < 4; ++j) acc[i][j] = (f32x4){0.f, 0.f, 0.f, 0.f};

    const int srow = lane >> 3, sch = lane & 7;   // staging lane -> (row-in-seg, chunk)

    for (int k0 = 0; k0 < 1024; k0 += 64) {
#pragma unroll
        for (int i = 0; i < 4; ++i) {
            int seg = wave * 4 + i;               // 16 segs of 8 rows
            int row = seg * 8 + srow;
            GLOAD_LDS16(X + (size_t)(m0 + row) * 1024 + k0 + sch * 8, &ldsA[seg * 512]);
            GLOAD_LDS16(W + (size_t)(n0 + row) * 1024 + k0 + sch * 8, &ldsB[seg * 512]);
        }
        __syncthreads();
#pragma unroll
        for (int ks = 0; ks < 2; ++ks) {
            bf16x8 af[4], bfr[4];
            int ch = ks * 4 + l4;
#pragma unroll
            for (int mi = 0; mi < 4; ++mi)
                af[mi] = *(const bf16x8*)&ldsA[(wr * 64 + mi * 16 + l15) * 64 + ch * 8];
#pragma unroll
            for (int ni = 0; ni < 4; ++ni)
                bfr[ni] = *(const bf16x8*)&ldsB[(wc * 64 + ni * 16 + l15) * 64 + ch * 8];
#pragma unroll
            for (int mi = 0; mi < 4; ++mi)
#pragma unroll
                for (int ni = 0; ni < 4; ++ni)
                    acc[mi][ni] = MFMA16(af[mi], bfr[ni], acc[mi][ni]);
        }
        __syncthreads();
    }
#pragma unroll
    for (int ni = 0; ni < 4; ++ni) {
        int n = n0 + wc * 64 + ni * 16 + l15;
        float bval = bias[n];
#pragma unroll
        for (int mi = 0; mi < 4; ++mi)
#pragma unroll
            for (int r = 0; r < 4; ++r) {
                int m = m0 + wr * 64 + mi * 16 + l4 * 4 + r;
                out[(size_t)m * 1024 + n] = (bf16)(acc[mi][ni][r] + bval);
            }
    }
}

// ---------------------------------------------------------------------------
// vp [B,S,H*128] -> vpT [B,H,128,S]
// ---------------------------------------------------------------------------
__global__ __launch_bounds__(256) void transpose_v(
    const bf16* __restrict__ vp, bf16* __restrict__ vpT)
{
    __shared__ __align__(16) bf16 t[64][80];
    const int tid = threadIdx.x;
    const int s0 = blockIdx.x * 64;
    const int db = blockIdx.y * 64;
    const int bh = blockIdx.z;
    const int b = bh >> 3, h = bh & 7;
#pragma unroll
    for (int rep = 0; rep < 2; ++rep) {
        int r = rep * 32 + (tid >> 3);
        int c = (tid & 7) * 8;
        *(bf16x8*)&t[r][c] =
            *(const bf16x8*)(vp + (size_t)(b * 1024 + s0 + r) * 1024 + h * 128 + db + c);
    }
    __syncthreads();
#pragma unroll
    for (int rep = 0; rep < 2; ++rep) {
        int dd = rep * 32 + (tid >> 3);
        int sc = (tid & 7) * 8;
        bf16x8 o;
#pragma unroll
        for (int j = 0; j < 8; ++j) o[j] = t[sc + j][dd];
        *(bf16x8*)(vpT + (size_t)((b * 8 + h) * 128 + db + dd) * 1024 + s0 + sc) = o;
    }
}

// ---------------------------------------------------------------------------
// Fused attention. Block = (b,h,64 q-rows), 4 waves x 16 rows. K/V tiles staged
// in LDS (XOR-swizzled), T14 reg-prefetch of next tile, XCD-bijective swizzle.
// ---------------------------------------------------------------------------
__global__ __launch_bounds__(256) void attn_kernel(
    const bf16* __restrict__ qp, const bf16* __restrict__ kp,
    const bf16* __restrict__ vpT, const int* __restrict__ mask,
    const float* __restrict__ Wo, const float* __restrict__ bo,
    float* __restrict__ out0, float* __restrict__ raw)
{
    __shared__ __align__(16) bf16 ldsK[64 * 128];      // [key][d], ch16 swizzled
    __shared__ __align__(16) bf16 ldsV[128 * 64];      // [d][key], ch8 swizzled
    __shared__ __align__(16) bf16 ldsP[4][16 * 64];    // per-wave P

    const int tid  = threadIdx.x;
    const int lane = tid & 63;
    const int l15  = lane & 15, l4 = lane >> 4;
    const int wave = tid >> 6;

    // bijective XCD swizzle: each XCD gets 8 full (b,h) heads (16 q-tiles each)
    int f = blockIdx.x;                 // 1024
    int xcd = f & 7, idx = f >> 3;      // idx 0..127
    int pair = xcd + 8 * (idx >> 4);    // 0..63
    int qt = idx & 15;
    int h = pair & 7, b = pair >> 3;
    const int q0 = qt * 64 + wave * 16;

    bf16x8 qf[4];
    const bf16* qbase = qp + (size_t)(b * 1024 + q0 + l15) * 1024 + h * 128 + l4 * 8;
#pragma unroll
    for (int ks = 0; ks < 4; ++ks) qf[ks] = *(const bf16x8*)(qbase + ks * 32);

    f32x4 ctx[8];
#pragma unroll
    for (int i = 0; i < 8; ++i) ctx[i] = (f32x4){0.f, 0.f, 0.f, 0.f};
    float m_run[4] = {-INFINITY, -INFINITY, -INFINITY, -INFINITY};
    float l_run[4] = {0.f, 0.f, 0.f, 0.f};

    const bf16* kbase_g = kp + (size_t)(b * 1024) * 1024 + h * 128;
    const bf16* vbase_g = vpT + (size_t)(b * 8 + h) * 128 * 1024;

    bf16x8 kreg[4], vreg[4];
    int mreg[4];
    auto load_tile = [&](int KB) {
#pragma unroll
        for (int j = 0; j < 4; ++j) {
            int fl = j * 256 + tid, rw = fl >> 4, ch = fl & 15;
            kreg[j] = *(const bf16x8*)(kbase_g + (size_t)(KB + rw) * 1024 + ch * 8);
        }
#pragma unroll
        for (int j = 0; j < 4; ++j) {
            int fl = j * 256 + tid, rw = fl >> 3, ch = fl & 7;
            vreg[j] = *(const bf16x8*)(vbase_g + (size_t)rw * 1024 + KB + ch * 8);
        }
#pragma unroll
        for (int nf = 0; nf < 4; ++nf) mreg[nf] = mask[b * 1024 + KB + nf * 16 + l15];
    };
    load_tile(0);

    const float scale = 0.08838834764831845f;  // 1/sqrt(128)

    for (int t = 0; t < 16; ++t) {
        const int kb = t * 64;
        __syncthreads();                       // tile t-1 fully consumed
#pragma unroll
        for (int j = 0; j < 4; ++j) {
            int fl = j * 256 + tid, rw = fl >> 4, ch = fl & 15;
            *(bf16x8*)&ldsK[rw * 128 + ((ch ^ (rw & 7)) << 3)] = kreg[j];
        }
#pragma unroll
        for (int j = 0; j < 4; ++j) {
            int fl = j * 256 + tid, rw = fl >> 3, ch = fl & 7;
            *(bf16x8*)&ldsV[rw * 64 + ((ch ^ (rw & 7)) << 3)] = vreg[j];
        }
        int msave[4];
#pragma unroll
        for (int nf = 0; nf < 4; ++nf) msave[nf] = mreg[nf];
        __syncthreads();
        if (t < 15) load_tile(kb + 64);        // prefetch hides under compute

        // ---- QK^T from LDS
        f32x4 s[4];
        __builtin_amdgcn_s_setprio(1);
#pragma unroll
        for (int nf = 0; nf < 4; ++nf) {
            int row = nf * 16 + l15;
            f32x4 a = (f32x4){0.f, 0.f, 0.f, 0.f};
#pragma unroll
            for (int ks = 0; ks < 4; ++ks) {
                bf16x8 kf = *(const bf16x8*)&ldsK[row * 128 + (((ks * 4 + l4) ^ (row & 7)) << 3)];
                a = MFMA16(qf[ks], kf, a);
            }
#pragma unroll
            for (int r = 0; r < 4; ++r) s[nf][r] = msave[nf] ? a[r] * scale : -1e9f;
        }
        __builtin_amdgcn_s_setprio(0);
        // ---- raw (pre-softmax masked) scores
#pragma unroll
        for (int nf = 0; nf < 4; ++nf) {
            int key = kb + nf * 16 + l15;
#pragma unroll
            for (int r = 0; r < 4; ++r)
                raw[(size_t)(b * 1024 + q0 + l4 * 4 + r) * 8192 + h * 1024 + key] = s[nf][r];
        }
        // ---- online softmax
#pragma unroll
        for (int r = 0; r < 4; ++r) {
            float pm = fmaxf(fmaxf(s[0][r], s[1][r]), fmaxf(s[2][r], s[3][r]));
            pm = fmaxf(pm, __shfl_xor(pm, 1));
            pm = fmaxf(pm, __shfl_xor(pm, 2));
            pm = fmaxf(pm, __shfl_xor(pm, 4));
            pm = fmaxf(pm, __shfl_xor(pm, 8));
            float mn = fmaxf(m_run[r], pm);
            float alpha = __expf(m_run[r] - mn);
            m_run[r] = mn;
            float rs = 0.f;
#pragma unroll
            for (int nf = 0; nf < 4; ++nf) {
                float p = __expf(s[nf][r] - mn);
                s[nf][r] = p;
                rs += p;
            }
            rs += __shfl_xor(rs, 1);
            rs += __shfl_xor(rs, 2);
            rs += __shfl_xor(rs, 4);
            rs += __shfl_xor(rs, 8);
            l_run[r] = l_run[r] * alpha + rs;
#pragma unroll
            for (int df = 0; df < 8; ++df) ctx[df][r] *= alpha;
        }
        // ---- P -> per-wave LDS (bf16, swizzled)
#pragma unroll
        for (int nf = 0; nf < 4; ++nf)
#pragma unroll
            for (int r = 0; r < 4; ++r) {
                int qw = l4 * 4 + r;
                int keyl = nf * 16 + l15;
                int chw = keyl >> 3;
                ldsP[wave][qw * 64 + ((chw ^ (qw & 7)) << 3) + (keyl & 7)] = (bf16)s[nf][r];
            }
        // ---- PV from LDS
        __builtin_amdgcn_s_setprio(1);
#pragma unroll
        for (int kstep = 0; kstep < 2; ++kstep) {
            bf16x8 pf = *(const bf16x8*)&ldsP[wave][l15 * 64 + (((kstep * 4 + l4) ^ (l15 & 7)) << 3)];
#pragma unroll
            for (int df = 0; df < 8; ++df) {
                int row = df * 16 + l15;
                bf16x8 vf = *(const bf16x8*)&ldsV[row * 64 + (((kstep * 4 + l4) ^ (row & 7)) << 3)];
                ctx[df] = MFMA16(pf, vf, ctx[df]);
            }
        }
        __builtin_amdgcn_s_setprio(0);
    }

    __syncthreads();                            // ldsK free for reuse as ctx buffer
    bf16* cbuf = &ldsK[wave * 2048];            // 16 q x 128 d per wave
    float invl[4];
#pragma unroll
    for (int r = 0; r < 4; ++r) invl[r] = 1.0f / l_run[r];
#pragma unroll
    for (int df = 0; df < 8; ++df)
#pragma unroll
        for (int r = 0; r < 4; ++r) {
            int qw = l4 * 4 + r;
            int dcol = df * 16 + l15;
            int chw = dcol >> 3;
            cbuf[qw * 128 + ((chw ^ (qw & 7)) << 3) + (dcol & 7)] = (bf16)(ctx[df][r] * invl[r]);
        }
    f32x4 oacc[8];
#pragma unroll
    for (int i = 0; i < 8; ++i) oacc[i] = (f32x4){0.f, 0.f, 0.f, 0.f};
#pragma unroll
    for (int ks = 0; ks < 4; ++ks) {
        int ch = ks * 4 + l4;
        bf16x8 cf = *(const bf16x8*)&cbuf[l15 * 128 + ((ch ^ (l15 & 7)) << 3)];
#pragma unroll
        for (int ef = 0; ef < 8; ++ef) {
            const float* wsrc = Wo + (ef * 16 + l15) * 128 + ks * 32 + l4 * 8;
            bf16x8 wf;
#pragma unroll
            for (int j = 0; j < 8; ++j) wf[j] = (bf16)wsrc[j];
            oacc[ef] = MFMA16(cf, wf, oacc[ef]);
        }
    }
#pragma unroll
    for (int ef = 0; ef < 8; ++ef) {
        float bias = bo[ef * 16 + l15];
#pragma unroll
        for (int r = 0; r < 4; ++r) {
            int qrow = q0 + l4 * 4 + r;
            out0[(size_t)(b * 1024 + qrow) * 1024 + h * 128 + ef * 16 + l15] =
                oacc[ef][r] + bias;
        }
    }
}

extern "C" void kernel_launch(void* const* d_in, const int* in_sizes, int n_in,
                              void* d_out, int out_size, void* d_ws, size_t ws_size,
                              hipStream_t stream) {
    const float* q    = (const float*)d_in[0];
    const float* k    = (const float*)d_in[1];
    const float* v    = (const float*)d_in[2];
    const int*   mask = (const int*)d_in[3];
    const float* Wq   = (const float*)d_in[4];
    const float* bq   = (const float*)d_in[5];
    const float* Wk   = (const float*)d_in[6];
    const float* bk   = (const float*)d_in[7];
    const float* Wv   = (const float*)d_in[8];
    const float* bv   = (const float*)d_in[9];
    const float* Wo   = (const float*)d_in[10];
    const float* bo   = (const float*)d_in[11];

    float* out0 = (float*)d_out;                       // [B,S,D]
    float* raw  = out0 + (size_t)B_ * S_ * D_;         // [B,S,H*S]

    // Scratch tensors that die before attn_kernel live in d_out's raw region
    // (268 MB, overwritten last). Tensors read by attn live in d_ws (48 MB, proven).
    char* rb = (char*)raw;
    bf16* xq  = (bf16*)(rb);
    bf16* xk  = (bf16*)(rb + (size_t)16 * 1048576);
    bf16* xv  = (bf16*)(rb + (size_t)32 * 1048576);
    bf16* wqb = (bf16*)(rb + (size_t)48 * 1048576);
    bf16* wkb = (bf16*)(rb + (size_t)50 * 1048576);
    bf16* wvb = (bf16*)(rb + (size_t)52 * 1048576);
    bf16* vp  = (bf16*)(rb + (size_t)54 * 1048576);

    bf16* qp  = (bf16*)d_ws;
    bf16* kp  = qp + (size_t)8388608;
    bf16* vpT = kp + (size_t)8388608;

    cast6<<<dim3(4096, 6), 256, 0, stream>>>(q, k, v, Wq, Wk, Wv, xq, xk, xv, wqb, wkb, wvb);
    proj_bf16<<<512, 256, 0, stream>>>(xq, wqb, bq, qp);
    proj_bf16<<<512, 256, 0, stream>>>(xk, wkb, bk, kp);
    proj_bf16<<<512, 256, 0, stream>>>(xv, wvb, bv, vp);
    transpose_v<<<dim3(16, 2, 64), 256, 0, stream>>>(vp, vpT);
    attn_kernel<<<1024, 256, 0, stream>>>(qp, kp, vpT, mask, Wo, bo, out0, raw);
}

// Round 4
// 581.383 us; speedup vs baseline: 1.3277x; 1.0980x over previous
//
#include <hip/hip_runtime.h>
#include <math.h>

#define B_ 8
#define S_ 1024
#define D_ 1024
#define H_ 8

typedef __bf16 bf16;
typedef __attribute__((ext_vector_type(8))) __bf16 bf16x8;
typedef __attribute__((ext_vector_type(4))) float f32x4;
typedef __attribute__((ext_vector_type(16))) float f32x16;

#define MFMA16(a, b, c) __builtin_amdgcn_mfma_f32_16x16x32_bf16((a), (b), (c), 0, 0, 0)
#define MFMA32(a, b, c) __builtin_amdgcn_mfma_f32_32x32x16_bf16((a), (b), (c), 0, 0, 0)
#define GLOAD_LDS16(src, dst)                                                            \
    __builtin_amdgcn_global_load_lds((const __attribute__((address_space(1))) void*)(src), \
                                     (__attribute__((address_space(3))) void*)(dst), 16, 0, 0)

// ---------------------------------------------------------------------------
// cast fp32 -> bf16 for q,k,v (8.4M each) and Wq,Wk,Wv (1M each)
// ---------------------------------------------------------------------------
__global__ __launch_bounds__(256) void cast6(
    const float* __restrict__ q, const float* __restrict__ k, const float* __restrict__ v,
    const float* __restrict__ Wq, const float* __restrict__ Wk, const float* __restrict__ Wv,
    bf16* __restrict__ xq, bf16* __restrict__ xk, bf16* __restrict__ xv,
    bf16* __restrict__ wq, bf16* __restrict__ wk, bf16* __restrict__ wv)
{
    int t = blockIdx.y;
    const float* src;
    bf16* dst;
    size_t n;
    switch (t) {
        case 0: src = q;  dst = xq; n = 8388608; break;
        case 1: src = k;  dst = xk; n = 8388608; break;
        case 2: src = v;  dst = xv; n = 8388608; break;
        case 3: src = Wq; dst = wq; n = 1048576; break;
        case 4: src = Wk; dst = wk; n = 1048576; break;
        default: src = Wv; dst = wv; n = 1048576; break;
    }
    size_t i0 = ((size_t)blockIdx.x * 256 + threadIdx.x) * 8;
    if (i0 >= n) return;
    f32x4 a = *(const f32x4*)(src + i0);
    f32x4 b = *(const f32x4*)(src + i0 + 4);
    bf16x8 o;
#pragma unroll
    for (int j = 0; j < 4; ++j) { o[j] = (bf16)a[j]; o[4 + j] = (bf16)b[j]; }
    *(bf16x8*)(dst + i0) = o;
}

// ---------------------------------------------------------------------------
// Merged bf16 GEMM for all three projections: 1536 blocks (which = 0,1,2).
// out[m,n] = (X[m,:].W[n,:] + bias[n]) * scale.  128x128 tile, BK=64,
// global_load_lds width16, linear LDS, XCD-chunked remap. q gets 1/sqrt(128).
// ---------------------------------------------------------------------------
__global__ __launch_bounds__(256) void proj3(
    const bf16* Xq, const bf16* Xk, const bf16* Xv,
    const bf16* Wqp, const bf16* Wkp, const bf16* Wvp,
    const float* bq, const float* bk, const float* bv,
    bf16* oq, bf16* ok, bf16* ov, float qscale)
{
    __shared__ __align__(16) bf16 ldsA[128 * 64];
    __shared__ __align__(16) bf16 ldsB[128 * 64];
    const int tid  = threadIdx.x;
    const int lane = tid & 63;
    const int l15  = lane & 15, l4 = lane >> 4;
    const int wave = tid >> 6;
    const int wr   = wave >> 1, wc = wave & 1;

    int f = blockIdx.x;                 // 1536
    int xcd = f & 7, r = f >> 3;        // r 0..191
    int which = r >> 6, idx = r & 63;   // which in dispatch order (temporal locality)
    const bf16* X = which == 0 ? Xq : (which == 1 ? Xk : Xv);
    const bf16* W = which == 0 ? Wqp : (which == 1 ? Wkp : Wvp);
    const float* bias = which == 0 ? bq : (which == 1 ? bk : bv);
    bf16* out = which == 0 ? oq : (which == 1 ? ok : ov);
    const float scale = which == 0 ? qscale : 1.0f;

    const int m0 = (xcd * 8 + (idx >> 3)) * 128;
    const int n0 = (idx & 7) * 128;

    f32x4 acc[4][4];
#pragma unroll
    for (int i = 0; i < 4; ++i)
#pragma unroll
        for (int j = 0; j < 4; ++j) acc[i][j] = (f32x4){0.f, 0.f, 0.f, 0.f};

    const int srow = lane >> 3, sch = lane & 7;

    for (int k0 = 0; k0 < 1024; k0 += 64) {
#pragma unroll
        for (int i = 0; i < 4; ++i) {
            int seg = wave * 4 + i;
            int row = seg * 8 + srow;
            GLOAD_LDS16(X + (size_t)(m0 + row) * 1024 + k0 + sch * 8, &ldsA[seg * 512]);
            GLOAD_LDS16(W + (size_t)(n0 + row) * 1024 + k0 + sch * 8, &ldsB[seg * 512]);
        }
        __syncthreads();
#pragma unroll
        for (int ks = 0; ks < 2; ++ks) {
            bf16x8 af[4], bfr[4];
            int ch = ks * 4 + l4;
#pragma unroll
            for (int mi = 0; mi < 4; ++mi)
                af[mi] = *(const bf16x8*)&ldsA[(wr * 64 + mi * 16 + l15) * 64 + ch * 8];
#pragma unroll
            for (int ni = 0; ni < 4; ++ni)
                bfr[ni] = *(const bf16x8*)&ldsB[(wc * 64 + ni * 16 + l15) * 64 + ch * 8];
#pragma unroll
            for (int mi = 0; mi < 4; ++mi)
#pragma unroll
                for (int ni = 0; ni < 4; ++ni)
                    acc[mi][ni] = MFMA16(af[mi], bfr[ni], acc[mi][ni]);
        }
        __syncthreads();
    }
#pragma unroll
    for (int ni = 0; ni < 4; ++ni) {
        int n = n0 + wc * 64 + ni * 16 + l15;
        float bval = bias[n];
#pragma unroll
        for (int mi = 0; mi < 4; ++mi)
#pragma unroll
            for (int rr = 0; rr < 4; ++rr) {
                int m = m0 + wr * 64 + mi * 16 + l4 * 4 + rr;
                out[(size_t)m * 1024 + n] = (bf16)((acc[mi][ni][rr] + bval) * scale);
            }
    }
}

// ---------------------------------------------------------------------------
// vp [B,S,H*128] -> vpT [B,H,128,S]
// ---------------------------------------------------------------------------
__global__ __launch_bounds__(256) void transpose_v(
    const bf16* __restrict__ vp, bf16* __restrict__ vpT)
{
    __shared__ __align__(16) bf16 t[64][80];
    const int tid = threadIdx.x;
    const int s0 = blockIdx.x * 64;
    const int db = blockIdx.y * 64;
    const int bh = blockIdx.z;
    const int b = bh >> 3, h = bh & 7;
#pragma unroll
    for (int rep = 0; rep < 2; ++rep) {
        int r = rep * 32 + (tid >> 3);
        int c = (tid & 7) * 8;
        *(bf16x8*)&t[r][c] =
            *(const bf16x8*)(vp + (size_t)(b * 1024 + s0 + r) * 1024 + h * 128 + db + c);
    }
    __syncthreads();
#pragma unroll
    for (int rep = 0; rep < 2; ++rep) {
        int dd = rep * 32 + (tid >> 3);
        int sc = (tid & 7) * 8;
        bf16x8 o;
#pragma unroll
        for (int j = 0; j < 8; ++j) o[j] = t[sc + j][dd];
        *(bf16x8*)(vpT + (size_t)((b * 8 + h) * 128 + db + dd) * 1024 + s0 + sc) = o;
    }
}

// ---------------------------------------------------------------------------
// Fused attention, swapped-operand 32x32 structure (m214-style).
// Block = (b,h,128 q-rows), 4 waves x 32 q-rows. Per wave:
//   scores^T = mfma32(K_frag, Q_frag): lane owns q=lane&31, k in regs.
//   softmax fully in-lane (+ one shfl_xor 32); P->B-frags via half-exchange.
//   ctx^T = mfma32(V^T_frag, P^T_frag); fused out-proj = mfma32(Wo, ctx^T).
// K/V LDS tiles XOR-swizzled 16-slot (2-way = free both sides).
// ---------------------------------------------------------------------------
__global__ __launch_bounds__(256, 2) void attn_kernel(
    const bf16* __restrict__ qp, const bf16* __restrict__ kp,
    const bf16* __restrict__ vpT, const int* __restrict__ mask,
    const float* __restrict__ Wo, const float* __restrict__ bo,
    float* __restrict__ out0, float* __restrict__ raw)
{
    __shared__ __align__(16) bf16 ldsK[64 * 128];   // [key][d] ch16 ^ (row&15)
    __shared__ __align__(16) bf16 ldsV[64 * 128];   // [d>>1][(d&1)*64+k] ch16 ^ (row&15)

    const int tid  = threadIdx.x;
    const int lane = tid & 63;
    const int l31  = lane & 31;
    const int hi   = lane >> 5;          // which 32-lane half
    const int wave = tid >> 6;

    // XCD swizzle: xcd = f&7; 8 heads per XCD, 8 q-tiles per head.
    int f = blockIdx.x;                  // 512
    int xcd = f & 7, idx = f >> 3;       // idx 0..63
    int pair = xcd + 8 * (idx >> 3);     // 0..63 (b,h)
    int qt = idx & 7;
    int h = pair & 7, b = pair >> 3;
    const int ql = qt * 128 + wave * 32 + l31;   // this lane's q row

    // Q B-frags: frag ds elem j <-> d = ds*16 + 8*hi + j  (qp pre-scaled)
    bf16x8 qf[8];
    const bf16* qrow = qp + (size_t)(b * 1024 + ql) * 1024 + h * 128 + hi * 8;
#pragma unroll
    for (int ds = 0; ds < 8; ++ds) qf[ds] = *(const bf16x8*)(qrow + ds * 16);

    f32x16 ctx[4];
#pragma unroll
    for (int dt = 0; dt < 4; ++dt)
#pragma unroll
        for (int i = 0; i < 16; ++i) ctx[dt][i] = 0.f;
    float m_run = -INFINITY, l_run = 0.f;

    const bf16* kbase = kp + (size_t)(b * 1024) * 1024 + h * 128;
    const bf16* vbase = vpT + (size_t)((b * 8 + h) * 128) * 1024;

    bf16x8 kreg[4], vreg[4];
    auto prefetch = [&](int KB) {
#pragma unroll
        for (int j = 0; j < 4; ++j) {
            int fl = j * 256 + tid;
            kreg[j] = *(const bf16x8*)(kbase + (size_t)(KB + (fl >> 4)) * 1024 + (fl & 15) * 8);
        }
#pragma unroll
        for (int j = 0; j < 4; ++j) {
            int fl = j * 256 + tid;
            vreg[j] = *(const bf16x8*)(vbase + (size_t)(fl >> 3) * 1024 + KB + (fl & 7) * 8);
        }
    };
    prefetch(0);

    for (int t = 0; t < 16; ++t) {
        const int kb = t * 64;
        __syncthreads();
#pragma unroll
        for (int j = 0; j < 4; ++j) {    // K tile: [64 key][128 d]
            int fl = j * 256 + tid;
            int row = fl >> 4, c = fl & 15;
            *(bf16x8*)&ldsK[row * 128 + ((c ^ (row & 15)) << 3)] = kreg[j];
        }
#pragma unroll
        for (int j = 0; j < 4; ++j) {    // V tile: two d-rows packed per LDS row
            int fl = j * 256 + tid;
            int d = fl >> 3, c8 = fl & 7;
            int lr = d >> 1, c = ((d & 1) << 3) | c8;
            *(bf16x8*)&ldsV[lr * 128 + ((c ^ (lr & 15)) << 3)] = vreg[j];
        }
        __syncthreads();
        if (t < 15) prefetch(kb + 64);

        // ---- scores^T: sa[mt] rows = keys mt*32+(r0+8r1+4hi), col = q = l31
        f32x16 sa[2];
#pragma unroll
        for (int mt = 0; mt < 2; ++mt)
#pragma unroll
            for (int i = 0; i < 16; ++i) sa[mt][i] = 0.f;
        __builtin_amdgcn_s_setprio(1);
#pragma unroll
        for (int mt = 0; mt < 2; ++mt) {
            int row = mt * 32 + l31;
#pragma unroll
            for (int ds = 0; ds < 8; ++ds) {
                int c = 2 * ds + hi;
                bf16x8 kf = *(const bf16x8*)&ldsK[row * 128 + ((c ^ (row & 15)) << 3)];
                sa[mt] = MFMA32(kf, qf[ds], sa[mt]);
            }
        }
        __builtin_amdgcn_s_setprio(0);

        // ---- mask select (exact reference semantics) + raw f32x4 stores
        float s[2][16];
        float* rawrow = raw + (size_t)(b * 1024 + ql) * 8192 + h * 1024 + kb;
#pragma unroll
        for (int mt = 0; mt < 2; ++mt)
#pragma unroll
            for (int r1 = 0; r1 < 4; ++r1) {
                int koff = mt * 32 + r1 * 8 + hi * 4;
                int4 mv = *(const int4*)(mask + b * 1024 + kb + koff);
                s[mt][r1 * 4 + 0] = mv.x ? sa[mt][r1 * 4 + 0] : -1e9f;
                s[mt][r1 * 4 + 1] = mv.y ? sa[mt][r1 * 4 + 1] : -1e9f;
                s[mt][r1 * 4 + 2] = mv.z ? sa[mt][r1 * 4 + 2] : -1e9f;
                s[mt][r1 * 4 + 3] = mv.w ? sa[mt][r1 * 4 + 3] : -1e9f;
                f32x4 st = {s[mt][r1 * 4 + 0], s[mt][r1 * 4 + 1],
                            s[mt][r1 * 4 + 2], s[mt][r1 * 4 + 3]};
                *(f32x4*)(rawrow + koff) = st;
            }

        // ---- online softmax, fully in-lane (+1 cross-half shfl)
        float pm = s[0][0];
#pragma unroll
        for (int mt = 0; mt < 2; ++mt)
#pragma unroll
            for (int i = 0; i < 16; ++i) pm = fmaxf(pm, s[mt][i]);
        pm = fmaxf(pm, __shfl_xor(pm, 32));
        if (!__all(pm <= m_run + 8.0f)) {        // T13 defer-max, THR=8
            float mn = fmaxf(m_run, pm);
            float al = __expf(m_run - mn);
#pragma unroll
            for (int dt = 0; dt < 4; ++dt)
#pragma unroll
                for (int i = 0; i < 16; ++i) ctx[dt][i] *= al;
            l_run *= al;
            m_run = mn;
        }
        float ps = 0.f;
#pragma unroll
        for (int mt = 0; mt < 2; ++mt)
#pragma unroll
            for (int i = 0; i < 16; ++i) {
                float p = __expf(s[mt][i] - m_run);
                s[mt][i] = p;
                ps += p;
            }
        ps += __shfl_xor(ps, 32);
        l_run += ps;

        // ---- P^T B-frags via half-exchange: frag ks elem j <-> k = ks*16+8hi+j
        bf16x8 pfrag[4];
#pragma unroll
        for (int mt = 0; mt < 2; ++mt)
#pragma unroll
            for (int sub = 0; sub < 2; ++sub) {
                float sv[4], rv[4];
#pragma unroll
                for (int j = 0; j < 4; ++j)
                    sv[j] = hi ? s[mt][sub * 8 + j] : s[mt][sub * 8 + 4 + j];
#pragma unroll
                for (int j = 0; j < 4; ++j) rv[j] = __shfl_xor(sv[j], 32);
                bf16x8 pf;
#pragma unroll
                for (int j = 0; j < 4; ++j) {
                    pf[j]     = (bf16)(hi ? rv[j] : s[mt][sub * 8 + j]);
                    pf[4 + j] = (bf16)(hi ? s[mt][sub * 8 + 4 + j] : rv[j]);
                }
                pfrag[mt * 2 + sub] = pf;
            }

        // ---- ctx^T += V^T P^T
        __builtin_amdgcn_s_setprio(1);
#pragma unroll
        for (int dt = 0; dt < 4; ++dt) {
            int d0 = dt * 32 + l31;
            int lr = d0 >> 1, cb = (d0 & 1) << 3;
#pragma unroll
            for (int ks = 0; ks < 4; ++ks) {
                int c = cb | (ks * 2 + hi);
                bf16x8 vf = *(const bf16x8*)&ldsV[lr * 128 + ((c ^ (lr & 15)) << 3)];
                ctx[dt] = MFMA32(vf, pfrag[ks], ctx[dt]);
            }
        }
        __builtin_amdgcn_s_setprio(0);
    }

    // ---- normalize (lane-local scalar), out-proj: out^T[e][q] = Wo . ctx^T
    float invl = 1.0f / l_run;
#pragma unroll
    for (int dt = 0; dt < 4; ++dt)
#pragma unroll
        for (int i = 0; i < 16; ++i) ctx[dt][i] *= invl;

    bf16x8 cb[8];                         // ctx^T B-frags: dsub elem j <-> d = dsub*16+8hi+j
#pragma unroll
    for (int dt = 0; dt < 4; ++dt)
#pragma unroll
        for (int sub = 0; sub < 2; ++sub) {
            float sv[4], rv[4];
#pragma unroll
            for (int j = 0; j < 4; ++j)
                sv[j] = hi ? ctx[dt][sub * 8 + j] : ctx[dt][sub * 8 + 4 + j];
#pragma unroll
            for (int j = 0; j < 4; ++j) rv[j] = __shfl_xor(sv[j], 32);
            bf16x8 cf;
#pragma unroll
            for (int j = 0; j < 4; ++j) {
                cf[j]     = (bf16)(hi ? rv[j] : ctx[dt][sub * 8 + j]);
                cf[4 + j] = (bf16)(hi ? ctx[dt][sub * 8 + 4 + j] : rv[j]);
            }
            cb[dt * 2 + sub] = cf;
        }

    f32x16 oacc[4];
#pragma unroll
    for (int et = 0; et < 4; ++et)
#pragma unroll
        for (int i = 0; i < 16; ++i) oacc[et][i] = 0.f;
#pragma unroll
    for (int et = 0; et < 4; ++et) {
        const float* wr = Wo + (et * 32 + l31) * 128 + hi * 8;
#pragma unroll
        for (int dsub = 0; dsub < 8; ++dsub) {
            f32x4 w0 = *(const f32x4*)(wr + dsub * 16);
            f32x4 w1 = *(const f32x4*)(wr + dsub * 16 + 4);
            bf16x8 wf;
#pragma unroll
            for (int j = 0; j < 4; ++j) { wf[j] = (bf16)w0[j]; wf[4 + j] = (bf16)w1[j]; }
            oacc[et] = MFMA32(wf, cb[dsub], oacc[et]);
        }
    }
    float* orow = out0 + (size_t)(b * 1024 + ql) * 1024 + h * 128;
#pragma unroll
    for (int et = 0; et < 4; ++et)
#pragma unroll
        for (int r1 = 0; r1 < 4; ++r1) {
            int eb = et * 32 + r1 * 8 + hi * 4;
            f32x4 bo4 = *(const f32x4*)(bo + eb);
            f32x4 st = {oacc[et][r1 * 4 + 0] + bo4[0], oacc[et][r1 * 4 + 1] + bo4[1],
                        oacc[et][r1 * 4 + 2] + bo4[2], oacc[et][r1 * 4 + 3] + bo4[3]};
            *(f32x4*)(orow + eb) = st;
        }
}

extern "C" void kernel_launch(void* const* d_in, const int* in_sizes, int n_in,
                              void* d_out, int out_size, void* d_ws, size_t ws_size,
                              hipStream_t stream) {
    const float* q    = (const float*)d_in[0];
    const float* k    = (const float*)d_in[1];
    const float* v    = (const float*)d_in[2];
    const int*   mask = (const int*)d_in[3];
    const float* Wq   = (const float*)d_in[4];
    const float* bq   = (const float*)d_in[5];
    const float* Wk   = (const float*)d_in[6];
    const float* bk   = (const float*)d_in[7];
    const float* Wv   = (const float*)d_in[8];
    const float* bv   = (const float*)d_in[9];
    const float* Wo   = (const float*)d_in[10];
    const float* bo   = (const float*)d_in[11];

    float* out0 = (float*)d_out;                       // [B,S,D]
    float* raw  = out0 + (size_t)B_ * S_ * D_;         // [B,S,H*S]

    // Scratch that dies before attn lives in d_out's raw region (overwritten last).
    char* rb = (char*)raw;
    bf16* xq  = (bf16*)(rb);
    bf16* xk  = (bf16*)(rb + (size_t)16 * 1048576);
    bf16* xv  = (bf16*)(rb + (size_t)32 * 1048576);
    bf16* wqb = (bf16*)(rb + (size_t)48 * 1048576);
    bf16* wkb = (bf16*)(rb + (size_t)50 * 1048576);
    bf16* wvb = (bf16*)(rb + (size_t)52 * 1048576);
    bf16* vp  = (bf16*)(rb + (size_t)54 * 1048576);

    bf16* qp  = (bf16*)d_ws;                           // scaled by 1/sqrt(128)
    bf16* kp  = qp + (size_t)8388608;
    bf16* vpT = kp + (size_t)8388608;

    const float scale = 0.08838834764831845f;          // 1/sqrt(128)

    cast6<<<dim3(4096, 6), 256, 0, stream>>>(q, k, v, Wq, Wk, Wv, xq, xk, xv, wqb, wkb, wvb);
    proj3<<<1536, 256, 0, stream>>>(xq, xk, xv, wqb, wkb, wvb, bq, bk, bv,
                                    qp, kp, vp, scale);
    transpose_v<<<dim3(16, 2, 64), 256, 0, stream>>>(vp, vpT);
    attn_kernel<<<512, 256, 0, stream>>>(qp, kp, vpT, mask, Wo, bo, out0, raw);
}